// Round 7
// baseline (177.401 us; speedup 1.0000x reference)
//
#include <hip/hip_runtime.h>
#include <math.h>

typedef __attribute__((ext_vector_type(4))) double d4;

// order-preserving float -> uint key (ascending float => ascending uint)
__device__ inline unsigned fkey(float f) {
  unsigned bits = __float_as_uint(f);
  return (bits & 0x80000000u) ? ~bits : (bits | 0x80000000u);
}

// ---------------------------------------------------------------------------
// Kernel 0: f64-MFMA layout probe (round-5/6 proven). flag<4 = D mapping id.
// ---------------------------------------------------------------------------
__global__ void probe_kernel(unsigned* __restrict__ flag) {
  __shared__ double A[16][4];
  __shared__ double B[4][16];
  const int l = threadIdx.x;
  {
    int i = l & 15, kk = l >> 4;
    A[i][kk] = (double)(i * 4 + kk + 1);
    B[kk][i] = (double)(i * 7 + kk * 3 + 2);
  }
  __syncthreads();
  const int l15 = l & 15, lk = l >> 4;
  double a = A[l15][lk];
  double b = B[lk][l15];
  d4 acc = (d4)0.0;
  acc = __builtin_amdgcn_mfma_f64_16x16x4f64(a, b, acc, 0, 0, 0);

  unsigned res = 4;
  for (int m = 3; m >= 0; --m) {
    bool ok = true;
#pragma unroll
    for (int i = 0; i < 4; ++i) {
      int tr_ = (m < 2) ? ((m == 0) ? 4 * lk + i : lk + 4 * i) : l15;
      int tc_ = (m < 2) ? l15 : ((m == 2) ? 4 * lk + i : lk + 4 * i);
      double ref = 0.0;
#pragma unroll
      for (int kk = 0; kk < 4; ++kk) ref += A[tr_][kk] * B[kk][tc_];
      ok = ok && (acc[i] == ref);
    }
    if (__all(ok)) res = (unsigned)m;
  }
  if (l == 0) flag[0] = res;
}

// ---------------------------------------------------------------------------
// Kernel 1a: logits = x @ W^T + b via v_mfma_f64_16x16x4_f64.
// 512 thr = 8 waves; wave w: rows (w&3)*16, cols (w>>2)*32 (2 acc tiles).
// fp32 LDS, packed [64][64] with XOR-quad swizzle (quad ^= row&15) applied on
// the GLOBAL source address at staging and on the read index (both sides).
// Double-buffered chunks (DC=64): ONE barrier per chunk; register prefetch
// 2 chunks ahead. fp32->fp64 cvt at fragment read (exact).
// Accumulation order identical to rounds 5/6 -> bitwise-same logits.
// ---------------------------------------------------------------------------
__global__ __launch_bounds__(512, 4) void logits_mfma_kernel(
    const float* __restrict__ x, const float* __restrict__ W,
    const float* __restrict__ bias, float* __restrict__ logits,
    float* __restrict__ logitsT, const unsigned* __restrict__ flag,
    int N, int D) {
  const unsigned fl = flag[0];
  if (fl >= 4u) return;   // layout unknown -> VALU kernel handles it

  __shared__ __attribute__((aligned(16))) float xbuf[2][64][64];  // 32 KB
  __shared__ __attribute__((aligned(16))) float wbuf[2][64][64];  // 32 KB

  const int tid = threadIdx.x;
  const int tok0 = blockIdx.x * 64;
  const int w = tid >> 6;        // wave 0..7
  const int l = tid & 63;
  const int l15 = l & 15;
  const int lk = l >> 4;
  const int rb = (w & 3) * 16;   // row base (tokens)
  const int cb = (w >> 2) * 32;  // col base (experts)

  d4 acc[2];
  acc[0] = (d4)0.0;
  acc[1] = (d4)0.0;

  // staging: slot = it*512+tid -> row = slot>>4 (0..63), q = slot&15.
  // LDS slot q holds source quad q ^ (row&15).
  const int srow0 = tid >> 4;          // it=0 row (0..31)
  const int srow1 = 32 + srow0;        // it=1 row (32..63)
  const int sq = tid & 15;
  const int sq0 = sq ^ (srow0 & 15);
  const int sq1 = sq ^ (srow1 & 15);

  const int nch = D >> 6;

  float4 rx[2], rw[2];
  // prefetch chunk 0
  rx[0] = *(const float4*)(x + (size_t)(tok0 + srow0) * D + (sq0 << 2));
  rx[1] = *(const float4*)(x + (size_t)(tok0 + srow1) * D + (sq1 << 2));
  rw[0] = *(const float4*)(W + (size_t)srow0 * D + (sq0 << 2));
  rw[1] = *(const float4*)(W + (size_t)srow1 * D + (sq1 << 2));
  // write chunk 0 -> buf 0
  *(float4*)(&xbuf[0][srow0][sq << 2]) = rx[0];
  *(float4*)(&xbuf[0][srow1][sq << 2]) = rx[1];
  *(float4*)(&wbuf[0][srow0][sq << 2]) = rw[0];
  *(float4*)(&wbuf[0][srow1][sq << 2]) = rw[1];
  // prefetch chunk 1
  if (nch > 1) {
    rx[0] = *(const float4*)(x + (size_t)(tok0 + srow0) * D + 64 + (sq0 << 2));
    rx[1] = *(const float4*)(x + (size_t)(tok0 + srow1) * D + 64 + (sq1 << 2));
    rw[0] = *(const float4*)(W + (size_t)srow0 * D + 64 + (sq0 << 2));
    rw[1] = *(const float4*)(W + (size_t)srow1 * D + 64 + (sq1 << 2));
  }
  __syncthreads();

  for (int c = 0; c < nch; ++c) {
    const int cbuf = c & 1;
    const int nb = cbuf ^ 1;
    // ---- write prefetched chunk c+1 into the other buffer ----
    if (c + 1 < nch) {
      *(float4*)(&xbuf[nb][srow0][sq << 2]) = rx[0];
      *(float4*)(&xbuf[nb][srow1][sq << 2]) = rx[1];
      *(float4*)(&wbuf[nb][srow0][sq << 2]) = rw[0];
      *(float4*)(&wbuf[nb][srow1][sq << 2]) = rw[1];
    }
    // ---- issue chunk c+2 global loads (hidden under MFMA) ----
    if (c + 2 < nch) {
      int kc = (c + 2) << 6;
      rx[0] = *(const float4*)(x + (size_t)(tok0 + srow0) * D + kc + (sq0 << 2));
      rx[1] = *(const float4*)(x + (size_t)(tok0 + srow1) * D + kc + (sq1 << 2));
      rw[0] = *(const float4*)(W + (size_t)srow0 * D + kc + (sq0 << 2));
      rw[1] = *(const float4*)(W + (size_t)srow1 * D + kc + (sq1 << 2));
    }
    // ---- MFMA phase: 16 K-steps of 4 from buf[cbuf] ----
    const float* xr = &xbuf[cbuf][rb + l15][0];
    const float* w0 = &wbuf[cbuf][cb + l15][0];
    const float* w1 = &wbuf[cbuf][cb + 16 + l15][0];
#pragma unroll
    for (int s = 0; s < 16; ++s) {
      const int qa = ((s ^ l15) << 2) | lk;
      double a = (double)xr[qa];
      double b0 = (double)w0[qa];
      double b1 = (double)w1[qa];
      acc[0] = __builtin_amdgcn_mfma_f64_16x16x4f64(a, b0, acc[0], 0, 0, 0);
      acc[1] = __builtin_amdgcn_mfma_f64_16x16x4f64(a, b1, acc[1], 0, 0, 0);
    }
    __syncthreads();
  }

  // ---- epilogue: probed D mapping, bias add (fp64), LDS round-trip ----
  float* ls = &xbuf[0][0][0];  // 64 x 65 fp32 view (16.6 KB), stride 65
#pragma unroll
  for (int ct = 0; ct < 2; ++ct) {
#pragma unroll
    for (int i = 0; i < 4; ++i) {
      int tr_, tc_;
      if (fl < 2u) { tc_ = l15; tr_ = (fl == 0u) ? 4 * lk + i : lk + 4 * i; }
      else         { tr_ = l15; tc_ = (fl == 2u) ? 4 * lk + i : lk + 4 * i; }
      int col = cb + ct * 16 + tc_;
      ls[(rb + tr_) * 65 + col] = (float)(acc[ct][i] + (double)bias[col]);
    }
  }
  __syncthreads();
  // row-major stores (1024 slots, 2/thread)
#pragma unroll
  for (int it = 0; it < 2; ++it) {
    int slot = it * 512 + tid;
    int row = slot >> 4, c4 = slot & 15;
    float4 v = {ls[row * 65 + c4 * 4 + 0], ls[row * 65 + c4 * 4 + 1],
                ls[row * 65 + c4 * 4 + 2], ls[row * 65 + c4 * 4 + 3]};
    *(float4*)(logits + (size_t)(tok0 + row) * 64 + c4 * 4) = v;
  }
  // transposed stores
#pragma unroll
  for (int it = 0; it < 2; ++it) {
    int slot = it * 512 + tid;
    int e = slot >> 4, t4 = slot & 15;
    float4 v = {ls[(t4 * 4 + 0) * 65 + e], ls[(t4 * 4 + 1) * 65 + e],
                ls[(t4 * 4 + 2) * 65 + e], ls[(t4 * 4 + 3) * 65 + e]};
    *(float4*)(logitsT + (size_t)e * N + tok0 + t4 * 4) = v;
  }
}

// ---------------------------------------------------------------------------
// Kernel 1b: VALU fp64 fallback (round-2 proven). Runs only if flag == 4.
// ---------------------------------------------------------------------------
__global__ __launch_bounds__(256) void logits_valu_kernel(
    const float* __restrict__ x, const float* __restrict__ W,
    const float* __restrict__ b, float* __restrict__ logits,
    float* __restrict__ logitsT, const unsigned* __restrict__ flag,
    int N, int D) {
  if (flag[0] < 4u) return;

  const int DC = 128;
  __shared__ __attribute__((aligned(16))) float xs[128][68];
  __shared__ __attribute__((aligned(16))) float wsm[128][68];
  const int tid = threadIdx.x;
  const int tok0 = blockIdx.x * 64;
  const int tr = tid & 15;
  const int tc = tid >> 4;
  double acc[4][4];
#pragma unroll
  for (int i = 0; i < 4; ++i)
#pragma unroll
    for (int j = 0; j < 4; ++j) acc[i][j] = 0.0;
  for (int kc = 0; kc < D; kc += DC) {
#pragma unroll
    for (int it = 0; it < 8; ++it) {
      int idx4 = it * 256 + tid;
      int row = idx4 >> 5;
      int c4 = idx4 & 31;
      float4 xv = *(const float4*)(x + (size_t)(tok0 + row) * D + kc + c4 * 4);
      float4 wv = *(const float4*)(W + (size_t)row * D + kc + c4 * 4);
      float xa[4] = {xv.x, xv.y, xv.z, xv.w};
      float wa[4] = {wv.x, wv.y, wv.z, wv.w};
#pragma unroll
      for (int jj = 0; jj < 4; ++jj) {
        int j = (jj + tid) & 3;
        float xe = (j == 0) ? xa[0] : (j == 1) ? xa[1] : (j == 2) ? xa[2] : xa[3];
        float we = (j == 0) ? wa[0] : (j == 1) ? wa[1] : (j == 2) ? wa[2] : wa[3];
        xs[c4 * 4 + j][row] = xe;
        wsm[c4 * 4 + j][row] = we;
      }
    }
    __syncthreads();
#pragma unroll 4
    for (int kk = 0; kk < DC; ++kk) {
      float4 xv = *(const float4*)&xs[kk][tr * 4];
      float4 wv = *(const float4*)&wsm[kk][tc * 4];
      const float xa[4] = {xv.x, xv.y, xv.z, xv.w};
      const float wa[4] = {wv.x, wv.y, wv.z, wv.w};
#pragma unroll
      for (int i = 0; i < 4; ++i) {
        double xd = (double)xa[i];
#pragma unroll
        for (int j = 0; j < 4; ++j)
          acc[i][j] = fma(xd, (double)wa[j], acc[i][j]);
      }
    }
    __syncthreads();
  }
  double bb[4] = {(double)b[tc * 4 + 0], (double)b[tc * 4 + 1],
                  (double)b[tc * 4 + 2], (double)b[tc * 4 + 3]};
  float f[4][4];
#pragma unroll
  for (int i = 0; i < 4; ++i)
#pragma unroll
    for (int j = 0; j < 4; ++j) f[i][j] = (float)(acc[i][j] + bb[j]);
#pragma unroll
  for (int i = 0; i < 4; ++i) {
    float4 o = {f[i][0], f[i][1], f[i][2], f[i][3]};
    *(float4*)(logits + (size_t)(tok0 + tr * 4 + i) * 64 + tc * 4) = o;
  }
#pragma unroll
  for (int j = 0; j < 4; ++j) {
    float4 o = {f[0][j], f[1][j], f[2][j], f[3][j]};
    *(float4*)(logitsT + (size_t)(tc * 4 + j) * N + tok0 + tr * 4) = o;
  }
}

// ---------------------------------------------------------------------------
// Kernel 2: per-expert k-th-largest via 2-bit-digit bisection (16 passes).
// ---------------------------------------------------------------------------
template <int KPT4>
__global__ __launch_bounds__(1024) void select_kernel(
    const float* __restrict__ logitsT, unsigned* __restrict__ ukeys,
    int N, int k) {
  __shared__ unsigned long long part[16];
  __shared__ unsigned s_cur;
  const int e = blockIdx.x;
  const int tid = threadIdx.x;
  const int wid = tid >> 6;
  const int lane = tid & 63;

  const float4* src = (const float4*)(logitsT + (size_t)e * N);
  unsigned key[KPT4 > 0 ? KPT4 * 4 : 4];
  if (KPT4 > 0) {
#pragma unroll
    for (int i = 0; i < (KPT4 > 0 ? KPT4 : 1); ++i) {
      float4 v = src[tid + i * 1024];
      key[i * 4 + 0] = fkey(v.x);
      key[i * 4 + 1] = fkey(v.y);
      key[i * 4 + 2] = fkey(v.z);
      key[i * 4 + 3] = fkey(v.w);
    }
  }

  unsigned cur = 0;
  for (int s = 30; s >= 0; s -= 2) {
    unsigned c1 = cur | (1u << s);
    unsigned c2 = cur | (2u << s);
    unsigned c3 = cur | (3u << s);
    unsigned n1 = 0, n2 = 0, n3 = 0;
    if (KPT4 > 0) {
#pragma unroll
      for (int i = 0; i < (KPT4 > 0 ? KPT4 * 4 : 1); ++i) {
        unsigned u = key[i];
        n1 += (u >= c1) ? 1u : 0u;
        n2 += (u >= c2) ? 1u : 0u;
        n3 += (u >= c3) ? 1u : 0u;
      }
    } else {
      for (int i = tid; i < (N >> 2); i += 1024) {
        float4 v = src[i];
        unsigned u0 = fkey(v.x), u1 = fkey(v.y), u2 = fkey(v.z), u3 = fkey(v.w);
        n1 += (u0 >= c1) + (u1 >= c1) + (u2 >= c1) + (u3 >= c1);
        n2 += (u0 >= c2) + (u1 >= c2) + (u2 >= c2) + (u3 >= c2);
        n3 += (u0 >= c3) + (u1 >= c3) + (u2 >= c3) + (u3 >= c3);
      }
    }
    unsigned long long pk = (unsigned long long)n1 |
                            ((unsigned long long)n2 << 21) |
                            ((unsigned long long)n3 << 42);
#pragma unroll
    for (int off = 32; off; off >>= 1) pk += __shfl_xor(pk, off);
    if (lane == 0) part[wid] = pk;
    __syncthreads();
    if (tid == 0) {
      unsigned long long t = 0;
#pragma unroll
      for (int w = 0; w < 16; ++w) t += part[w];
      unsigned m1 = (unsigned)(t & 0x1FFFFFu);
      unsigned m2 = (unsigned)((t >> 21) & 0x1FFFFFu);
      unsigned m3 = (unsigned)(t >> 42);
      unsigned kk = (unsigned)k;
      unsigned nxt = cur;
      if (m3 >= kk) nxt = c3;
      else if (m2 >= kk) nxt = c2;
      else if (m1 >= kk) nxt = c1;
      s_cur = nxt;
    }
    __syncthreads();
    cur = s_cur;
  }
  if (tid == 0) ukeys[e] = cur;
}

// ---------------------------------------------------------------------------
// Kernel 3: one wave per token; lane = expert; candidate iff key >= ukeys[e].
// ---------------------------------------------------------------------------
__global__ __launch_bounds__(256) void assign_kernel(
    const float* __restrict__ logits, const unsigned* __restrict__ ukeys,
    float* __restrict__ out, int N) {
  const int lane = threadIdx.x & 63;
  const int token = blockIdx.x * 4 + (threadIdx.x >> 6);

  float v = logits[(size_t)token * 64 + lane];
  unsigned u = fkey(v);
  bool cand = (u >= ukeys[lane]);
  float cv = cand ? v : -INFINITY;
  float m = cv;
#pragma unroll
  for (int off = 32; off; off >>= 1) m = fmaxf(m, __shfl_xor(m, off));
  unsigned long long mask = __ballot(cand && (v == m));
  bool sel = (mask != 0ull);
  int minexp = sel ? (__ffsll((long long)mask) - 1) : -1;

  if (lane == 0) {
    out[token] = sel ? m : 0.0f;
    out[N + token] = (float)minexp;
    out[2 * N + token] = sel ? 1.0f : 0.0f;
  }
}

// ---------------------------------------------------------------------------
// Kernel 4: counts (LDS histogram, single block) + load-balance loss, fused.
// ---------------------------------------------------------------------------
__global__ __launch_bounds__(1024) void count_loss_kernel(
    const float* __restrict__ assigned, float* __restrict__ out, int N) {
  __shared__ unsigned hist[16][64];
  const int tid = threadIdx.x;
  const int wid = tid >> 6;
  hist[tid >> 6][tid & 63] = 0u;
  __syncthreads();
  for (int i = tid; i < N; i += 1024) {
    int e = (int)assigned[i];
    if (e >= 0) atomicAdd(&hist[wid][e], 1u);
  }
  __syncthreads();
  if (tid < 64) {
    unsigned c = 0;
#pragma unroll
    for (int w = 0; w < 16; ++w) c += hist[w][tid];
    double cd = (double)c;
    double s = cd;
#pragma unroll
    for (int off = 32; off; off >>= 1) s += __shfl_xor(s, off);
    double mean = s / 64.0;
    double d = cd - mean;
    d = d * d;
#pragma unroll
    for (int off = 32; off; off >>= 1) d += __shfl_xor(d, off);
    if (tid == 0) out[3 * (size_t)N] = (float)((d / 64.0) / (mean + 1e-9));
  }
}

extern "C" void kernel_launch(void* const* d_in, const int* in_sizes, int n_in,
                              void* d_out, int out_size, void* d_ws, size_t ws_size,
                              hipStream_t stream) {
  const float* x = (const float*)d_in[0];
  const float* W = (const float*)d_in[1];
  const float* b = (const float*)d_in[2];

  const int E = in_sizes[2];      // 64
  const int D = in_sizes[1] / E;  // 1024
  const int N = in_sizes[0] / D;  // 32768

  int k = (int)((double)N / (double)(E > 1 ? E : 1) * 1.2);
  if (k < 1) k = 1;
  if (k > N) k = N;               // 614

  const size_t NE = (size_t)N * E;
  float* out = (float*)d_out;

  float* logits = (float*)d_ws;        // N*E fp32 (8 MB)
  float* logitsT = logits + NE;        // N*E fp32 (8 MB)
  unsigned* ukeys = (unsigned*)(logitsT + NE);
  unsigned* flag = ukeys + 64;

  probe_kernel<<<1, 64, 0, stream>>>(flag);
  logits_mfma_kernel<<<N / 64, 512, 0, stream>>>(x, W, b, logits, logitsT,
                                                 flag, N, D);
  logits_valu_kernel<<<N / 64, 256, 0, stream>>>(x, W, b, logits, logitsT,
                                                 flag, N, D);
  if (N == 32768)
    select_kernel<8><<<64, 1024, 0, stream>>>(logitsT, ukeys, N, k);
  else
    select_kernel<0><<<64, 1024, 0, stream>>>(logitsT, ukeys, N, k);
  assign_kernel<<<N / 4, 256, 0, stream>>>(logits, ukeys, out, N);
  count_loss_kernel<<<1, 1024, 0, stream>>>(out + N, out, N);
}

// Round 8
// 130.950 us; speedup vs baseline: 1.3547x; 1.3547x over previous
//
#include <hip/hip_runtime.h>
#include <math.h>

typedef __attribute__((ext_vector_type(4))) double d4;

// order-preserving float -> uint key (ascending float => ascending uint)
__device__ inline unsigned fkey(float f) {
  unsigned bits = __float_as_uint(f);
  return (bits & 0x80000000u) ? ~bits : (bits | 0x80000000u);
}

// ---------------------------------------------------------------------------
// Kernel 1: logits = x @ W^T + b via v_mfma_f64_16x16x4_f64 (round-6 proven
// structure), with the f64-MFMA layout PROBE fused in (wave 0, per block).
// 512 thr = 8 waves; wave w: rows (w&3)*16, cols (w>>2)*32 (2 acc tiles).
// DC=64 K-chunks staged in LDS as fp64 (cvt once at staging); register
// prefetch double buffering; two barriers per chunk.
// If the probe finds no valid D mapping (never observed on gfx950), an
// inline fp64 VALU fallback computes the same tile (same accumulation
// order as the round-2 proven kernel).
// ---------------------------------------------------------------------------
__global__ __launch_bounds__(512, 4) void logits_fused_kernel(
    const float* __restrict__ x, const float* __restrict__ W,
    const float* __restrict__ bias, float* __restrict__ logits,
    float* __restrict__ logitsT, int N, int D) {
  __shared__ __attribute__((aligned(16))) double xs64[64 * 66];
  __shared__ __attribute__((aligned(16))) double ws64[64 * 66];
  __shared__ unsigned s_fl;

  const int tid = threadIdx.x;
  const int tok0 = blockIdx.x * 64;
  const int l = tid & 63;
  const int l15 = l & 15;
  const int lk = l >> 4;

  // ---- fused probe: wave 0, scratch in ws64 ----
  double* pA = ws64;        // [16][4]
  double* pB = ws64 + 64;   // [4][16]
  if (tid < 64) {
    pA[l15 * 4 + lk] = (double)(l15 * 4 + lk + 1);
    pB[lk * 16 + l15] = (double)(l15 * 7 + lk * 3 + 2);
  }
  __syncthreads();
  if (tid < 64) {
    double a = pA[l15 * 4 + lk];
    double b = pB[lk * 16 + l15];
    d4 pacc = (d4)0.0;
    pacc = __builtin_amdgcn_mfma_f64_16x16x4f64(a, b, pacc, 0, 0, 0);
    unsigned res = 4;
    for (int m = 3; m >= 0; --m) {
      bool ok = true;
#pragma unroll
      for (int i = 0; i < 4; ++i) {
        int tr_ = (m < 2) ? ((m == 0) ? 4 * lk + i : lk + 4 * i) : l15;
        int tc_ = (m < 2) ? l15 : ((m == 2) ? 4 * lk + i : lk + 4 * i);
        double ref = 0.0;
#pragma unroll
        for (int kk = 0; kk < 4; ++kk) ref += pA[tr_ * 4 + kk] * pB[kk * 16 + tc_];
        ok = ok && (pacc[i] == ref);
      }
      if (__all(ok)) res = (unsigned)m;
    }
    if (l == 0) s_fl = res;
  }
  __syncthreads();
  const unsigned fl = s_fl;
  __syncthreads();   // ws64 probe scratch dead before staging reuses it

  if (fl < 4u) {
    // ================= MFMA path (round-6 proven) =================
    const int w = tid >> 6;        // wave 0..7
    const int rb = (w & 3) * 16;   // row base
    const int cb = (w >> 2) * 32;  // col base

    d4 acc[2];
    acc[0] = (d4)0.0;
    acc[1] = (d4)0.0;

    const int r0 = tid >> 4;       // 0..31
    const int c40 = tid & 15;

    float4 rx0, rx1, rw0, rw1;
    rx0 = *(const float4*)(x + (size_t)(tok0 + r0) * D + c40 * 4);
    rx1 = *(const float4*)(x + (size_t)(tok0 + 32 + r0) * D + c40 * 4);
    rw0 = *(const float4*)(W + (size_t)r0 * D + c40 * 4);
    rw1 = *(const float4*)(W + (size_t)(32 + r0) * D + c40 * 4);

    const int nch = D >> 6;
    const int xa0 = (rb + l15) * 66 + lk;
    const int ba0 = (cb + l15) * 66 + lk;

    for (int c = 0; c < nch; ++c) {
      // ---- write prefetched chunk to LDS (fp32 -> fp64, exact) ----
      {
        double* d0 = xs64 + r0 * 66 + c40 * 4;
        *(double2*)(d0) = make_double2((double)rx0.x, (double)rx0.y);
        *(double2*)(d0 + 2) = make_double2((double)rx0.z, (double)rx0.w);
        double* d1 = xs64 + (32 + r0) * 66 + c40 * 4;
        *(double2*)(d1) = make_double2((double)rx1.x, (double)rx1.y);
        *(double2*)(d1 + 2) = make_double2((double)rx1.z, (double)rx1.w);
        double* e0 = ws64 + r0 * 66 + c40 * 4;
        *(double2*)(e0) = make_double2((double)rw0.x, (double)rw0.y);
        *(double2*)(e0 + 2) = make_double2((double)rw0.z, (double)rw0.w);
        double* e1 = ws64 + (32 + r0) * 66 + c40 * 4;
        *(double2*)(e1) = make_double2((double)rw1.x, (double)rw1.y);
        *(double2*)(e1 + 2) = make_double2((double)rw1.z, (double)rw1.w);
      }
      __syncthreads();
      // ---- issue next chunk's global loads (hidden under MFMA) ----
      if (c + 1 < nch) {
        int kc = (c + 1) << 6;
        rx0 = *(const float4*)(x + (size_t)(tok0 + r0) * D + kc + c40 * 4);
        rx1 = *(const float4*)(x + (size_t)(tok0 + 32 + r0) * D + kc + c40 * 4);
        rw0 = *(const float4*)(W + (size_t)r0 * D + kc + c40 * 4);
        rw1 = *(const float4*)(W + (size_t)(32 + r0) * D + kc + c40 * 4);
      }
      // ---- MFMA phase: 16 K-steps of 4 ----
#pragma unroll
      for (int s = 0; s < 16; ++s) {
        double a = xs64[xa0 + 4 * s];
        double b0 = ws64[ba0 + 4 * s];
        double b1 = ws64[ba0 + 16 * 66 + 4 * s];
        acc[0] = __builtin_amdgcn_mfma_f64_16x16x4f64(a, b0, acc[0], 0, 0, 0);
        acc[1] = __builtin_amdgcn_mfma_f64_16x16x4f64(a, b1, acc[1], 0, 0, 0);
      }
      __syncthreads();
    }

    // ---- epilogue: probed D mapping, bias add (fp64), LDS round-trip ----
    float* ls = (float*)xs64;  // 64 x 68 fp32 view
#pragma unroll
    for (int ct = 0; ct < 2; ++ct) {
#pragma unroll
      for (int i = 0; i < 4; ++i) {
        int tr_, tc_;
        if (fl < 2u) { tc_ = l15; tr_ = (fl == 0u) ? 4 * lk + i : lk + 4 * i; }
        else         { tr_ = l15; tc_ = (fl == 2u) ? 4 * lk + i : lk + 4 * i; }
        int col = cb + ct * 16 + tc_;
        ls[(rb + tr_) * 68 + col] = (float)(acc[ct][i] + (double)bias[col]);
      }
    }
    __syncthreads();
    // row-major stores (1024 slots, 2/thread)
#pragma unroll
    for (int it = 0; it < 2; ++it) {
      int slot = it * 512 + tid;
      int row = slot >> 4, c4 = slot & 15;
      float4 v = {ls[row * 68 + c4 * 4 + 0], ls[row * 68 + c4 * 4 + 1],
                  ls[row * 68 + c4 * 4 + 2], ls[row * 68 + c4 * 4 + 3]};
      *(float4*)(logits + (size_t)(tok0 + row) * 64 + c4 * 4) = v;
    }
    // transposed stores
#pragma unroll
    for (int it = 0; it < 2; ++it) {
      int slot = it * 512 + tid;
      int e = slot >> 4, t4 = slot & 15;
      float4 v = {ls[(t4 * 4 + 0) * 68 + e], ls[(t4 * 4 + 1) * 68 + e],
                  ls[(t4 * 4 + 2) * 68 + e], ls[(t4 * 4 + 3) * 68 + e]};
      *(float4*)(logitsT + (size_t)e * N + tok0 + t4 * 4) = v;
    }
  } else {
    // ============ inline VALU fp64 fallback (never expected) ============
    for (int o = tid; o < 64 * 64; o += 512) {
      int row = o >> 6, col = o & 63;
      const float* xp = x + (size_t)(tok0 + row) * D;
      const float* wp = W + (size_t)col * D;
      double s = 0.0;
      for (int kk = 0; kk < D; ++kk)
        s = fma((double)xp[kk], (double)wp[kk], s);
      float v = (float)(s + (double)bias[col]);
      logits[(size_t)(tok0 + row) * 64 + col] = v;
      logitsT[(size_t)col * N + tok0 + row] = v;
    }
  }
}

// ---------------------------------------------------------------------------
// Kernel 2: per-expert k-th-largest via 2-bit-digit bisection (16 passes).
// No atomics: per-thread compare counts, packed u64 wave+block reduction.
// ---------------------------------------------------------------------------
template <int KPT4>
__global__ __launch_bounds__(1024) void select_kernel(
    const float* __restrict__ logitsT, unsigned* __restrict__ ukeys,
    int N, int k) {
  __shared__ unsigned long long part[16];
  __shared__ unsigned s_cur;
  const int e = blockIdx.x;
  const int tid = threadIdx.x;
  const int wid = tid >> 6;
  const int lane = tid & 63;

  const float4* src = (const float4*)(logitsT + (size_t)e * N);
  unsigned key[KPT4 > 0 ? KPT4 * 4 : 4];
  if (KPT4 > 0) {
#pragma unroll
    for (int i = 0; i < (KPT4 > 0 ? KPT4 : 1); ++i) {
      float4 v = src[tid + i * 1024];
      key[i * 4 + 0] = fkey(v.x);
      key[i * 4 + 1] = fkey(v.y);
      key[i * 4 + 2] = fkey(v.z);
      key[i * 4 + 3] = fkey(v.w);
    }
  }

  unsigned cur = 0;
  for (int s = 30; s >= 0; s -= 2) {
    unsigned c1 = cur | (1u << s);
    unsigned c2 = cur | (2u << s);
    unsigned c3 = cur | (3u << s);
    unsigned n1 = 0, n2 = 0, n3 = 0;
    if (KPT4 > 0) {
#pragma unroll
      for (int i = 0; i < (KPT4 > 0 ? KPT4 * 4 : 1); ++i) {
        unsigned u = key[i];
        n1 += (u >= c1) ? 1u : 0u;
        n2 += (u >= c2) ? 1u : 0u;
        n3 += (u >= c3) ? 1u : 0u;
      }
    } else {
      for (int i = tid; i < (N >> 2); i += 1024) {
        float4 v = src[i];
        unsigned u0 = fkey(v.x), u1 = fkey(v.y), u2 = fkey(v.z), u3 = fkey(v.w);
        n1 += (u0 >= c1) + (u1 >= c1) + (u2 >= c1) + (u3 >= c1);
        n2 += (u0 >= c2) + (u1 >= c2) + (u2 >= c2) + (u3 >= c2);
        n3 += (u0 >= c3) + (u1 >= c3) + (u2 >= c3) + (u3 >= c3);
      }
    }
    unsigned long long pk = (unsigned long long)n1 |
                            ((unsigned long long)n2 << 21) |
                            ((unsigned long long)n3 << 42);
#pragma unroll
    for (int off = 32; off; off >>= 1) pk += __shfl_xor(pk, off);
    if (lane == 0) part[wid] = pk;
    __syncthreads();
    if (tid == 0) {
      unsigned long long t = 0;
#pragma unroll
      for (int w = 0; w < 16; ++w) t += part[w];
      unsigned m1 = (unsigned)(t & 0x1FFFFFu);
      unsigned m2 = (unsigned)((t >> 21) & 0x1FFFFFu);
      unsigned m3 = (unsigned)(t >> 42);
      unsigned kk = (unsigned)k;
      unsigned nxt = cur;
      if (m3 >= kk) nxt = c3;
      else if (m2 >= kk) nxt = c2;
      else if (m1 >= kk) nxt = c1;
      s_cur = nxt;
    }
    __syncthreads();
    cur = s_cur;
  }
  if (tid == 0) ukeys[e] = cur;
}

// ---------------------------------------------------------------------------
// Kernel 3: one wave per token; lane = expert; candidate iff key >= ukeys[e].
// ---------------------------------------------------------------------------
__global__ __launch_bounds__(256) void assign_kernel(
    const float* __restrict__ logits, const unsigned* __restrict__ ukeys,
    float* __restrict__ out, int N) {
  const int lane = threadIdx.x & 63;
  const int token = blockIdx.x * 4 + (threadIdx.x >> 6);

  float v = logits[(size_t)token * 64 + lane];
  unsigned u = fkey(v);
  bool cand = (u >= ukeys[lane]);
  float cv = cand ? v : -INFINITY;
  float m = cv;
#pragma unroll
  for (int off = 32; off; off >>= 1) m = fmaxf(m, __shfl_xor(m, off));
  unsigned long long mask = __ballot(cand && (v == m));
  bool sel = (mask != 0ull);
  int minexp = sel ? (__ffsll((long long)mask) - 1) : -1;

  if (lane == 0) {
    out[token] = sel ? m : 0.0f;
    out[N + token] = (float)minexp;
    out[2 * N + token] = sel ? 1.0f : 0.0f;
  }
}

// ---------------------------------------------------------------------------
// Kernel 4: counts (LDS histogram, single block, float4 reads) + loss, fused.
// ---------------------------------------------------------------------------
__global__ __launch_bounds__(1024) void count_loss_kernel(
    const float* __restrict__ assigned, float* __restrict__ out, int N) {
  __shared__ unsigned hist[16][64];
  const int tid = threadIdx.x;
  const int wid = tid >> 6;
  hist[wid][tid & 63] = 0u;
  __syncthreads();
  const float4* src = (const float4*)assigned;
  for (int i = tid; i < (N >> 2); i += 1024) {
    float4 v = src[i];
    int e0 = (int)v.x, e1 = (int)v.y, e2 = (int)v.z, e3 = (int)v.w;
    if (e0 >= 0) atomicAdd(&hist[wid][e0], 1u);
    if (e1 >= 0) atomicAdd(&hist[wid][e1], 1u);
    if (e2 >= 0) atomicAdd(&hist[wid][e2], 1u);
    if (e3 >= 0) atomicAdd(&hist[wid][e3], 1u);
  }
  __syncthreads();
  if (tid < 64) {
    unsigned c = 0;
#pragma unroll
    for (int w = 0; w < 16; ++w) c += hist[w][tid];
    double cd = (double)c;
    double s = cd;
#pragma unroll
    for (int off = 32; off; off >>= 1) s += __shfl_xor(s, off);
    double mean = s / 64.0;
    double d = cd - mean;
    d = d * d;
#pragma unroll
    for (int off = 32; off; off >>= 1) d += __shfl_xor(d, off);
    if (tid == 0) out[3 * (size_t)N] = (float)((d / 64.0) / (mean + 1e-9));
  }
}

extern "C" void kernel_launch(void* const* d_in, const int* in_sizes, int n_in,
                              void* d_out, int out_size, void* d_ws, size_t ws_size,
                              hipStream_t stream) {
  const float* x = (const float*)d_in[0];
  const float* W = (const float*)d_in[1];
  const float* b = (const float*)d_in[2];

  const int E = in_sizes[2];      // 64
  const int D = in_sizes[1] / E;  // 1024
  const int N = in_sizes[0] / D;  // 32768

  int k = (int)((double)N / (double)(E > 1 ? E : 1) * 1.2);
  if (k < 1) k = 1;
  if (k > N) k = N;               // 614

  const size_t NE = (size_t)N * E;
  float* out = (float*)d_out;

  float* logits = (float*)d_ws;        // N*E fp32 (8 MB)
  float* logitsT = logits + NE;        // N*E fp32 (8 MB)
  unsigned* ukeys = (unsigned*)(logitsT + NE);

  logits_fused_kernel<<<N / 64, 512, 0, stream>>>(x, W, b, logits, logitsT,
                                                  N, D);
  if (N == 32768)
    select_kernel<8><<<64, 1024, 0, stream>>>(logitsT, ukeys, N, k);
  else
    select_kernel<0><<<64, 1024, 0, stream>>>(logitsT, ukeys, N, k);
  assign_kernel<<<N / 4, 256, 0, stream>>>(logits, ukeys, out, N);
  count_loss_kernel<<<1, 1024, 0, stream>>>(out + N, out, N);
}